// Round 8
// baseline (8890.616 us; speedup 1.0000x reference)
//
#include <hip/hip_runtime.h>
#include <stdint.h>

typedef unsigned short u16;
typedef unsigned int   u32;

// problem dims
#define TB_ 8      // batch
#define NN_ 256    // state n
#define DD_ 684    // context depth d
#define PP_ 576    // H*W = 12*48

// workspace layout (bytes). Region0 [0, 1486848) is time-shared:
//   phase1: UaCT (f32 [684][512], 1400832 B)  -- k_tran writes, k_pctx reads
//   phase2: sb @0 (786432 B) + buf @786432 (700416 B) -- k_sb/k_main (after k_pctx)
#define OFF_SB    0u
#define OFF_TRAN  0u
#define OFF_BUF   786432u
#define OFF_PCTX  1486848u    // f32 [b][p(576)][a(512)] = 9437184 B
#define OFF_FKT   10924032u   // f32 [tap(9)][a(512)] = 18432 B
#define OFF_FLG   10942464u   // int dtype flag
#define WS_NEED   10942480u   // < 11288592 proven available in R6/R7

// output offsets (elements, f32)
#define OFF_H2   0
#define OFF_CTC  65536
#define OFF_CTP  240640
#define OFF_AL   415744
#define OFF_APO  563200

__device__ __forceinline__ float b2f(u16 v){ union{u32 i; float f;} x; x.i = ((u32)v)<<16; return x.f; }
__device__ __forceinline__ float gld(const void* p, size_t i, int f32){
  if (f32) return ((const float*)p)[i];
  return b2f(((const u16*)p)[i]);
}
__device__ __forceinline__ float bl(u32 v){ union{u32 i; float f;} x; x.i = v<<16; return x.f; }
__device__ __forceinline__ float bh(u32 v){ union{u32 i; float f;} x; x.i = v & 0xFFFF0000u; return x.f; }

__device__ __forceinline__ float rcpf(float x){ return __builtin_amdgcn_rcpf(x); }
__device__ __forceinline__ float sigm(float x){
  x = fminf(fmaxf(x, -30.f), 30.f);
  return rcpf(1.f + __expf(-x));
}
__device__ __forceinline__ float tanh_c(float x){
  x = fminf(fmaxf(x, -15.f), 15.f);
  float e = __expf(2.f*x);
  return 1.f - 2.f*rcpf(e + 1.f);
}

// bf16-row helpers (fallback path)
__device__ __forceinline__ float dot8(uint4 u, const float* s){
  float a = fmaf(bl(u.x), s[0], bh(u.x)*s[1]);
  a = fmaf(bl(u.y), s[2], a); a = fmaf(bh(u.y), s[3], a);
  a = fmaf(bl(u.z), s[4], a); a = fmaf(bh(u.z), s[5], a);
  a = fmaf(bl(u.w), s[6], a); a = fmaf(bh(u.w), s[7], a);
  return a;
}
__device__ __forceinline__ float dot4t(uint2 u, const float* s, float a){
  a = fmaf(bl(u.x), s[0], a); a = fmaf(bh(u.x), s[1], a);
  a = fmaf(bl(u.y), s[2], a); a = fmaf(bh(u.y), s[3], a);
  return a;
}
// f32-row dot (16B-aligned w, n % 4 == 0), d-ascending accumulation order
__device__ __forceinline__ float dotf(const float* w, const float* s, int n){
  float a = 0.f;
  #pragma unroll 4
  for (int k=0;k<n;k+=4){
    float4 u = *(const float4*)(w+k);
    a = fmaf(u.x, s[k], a);   a = fmaf(u.y, s[k+1], a);
    a = fmaf(u.z, s[k+2], a); a = fmaf(u.w, s[k+3], a);
  }
  return a;
}
// dual-dtype row dot of length n
__device__ __forceinline__ float dotw(const void* W, size_t row_off, const float* s, int n, int f32){
  if (f32) return dotf((const float*)W + row_off, s, n);
  const u16* r = (const u16*)W + row_off;
  float a = 0.f;
  int k = 0;
  for (; k+8 <= n; k += 8) a += dot8(*(const uint4*)(r+k), s+k);
  if (k < n) a = dot4t(*(const uint2*)(r+k), s+k, a);
  return a;
}

// ---------------- dtype detector ----------------
__global__ void k_detect(const u16* __restrict__ ctx_u16, int* __restrict__ flag){
  __shared__ int cnt;
  if (threadIdx.x == 0) cnt = 0;
  __syncthreads();
  int bad = 0;
  for (int k = threadIdx.x; k < 512; k += 256){
    u16 v = ctx_u16[k];
    int e = (v >> 7) & 0xFF;
    bool sane = (v == 0u) || (v == 0x8000u) || (e >= 102 && e <= 141);
    if (!sane) bad++;
  }
  atomicAdd(&cnt, bad);
  __syncthreads();
  if (threadIdx.x == 0) flag[0] = (cnt > 64) ? 1 : 0;
}

// ---------------- precompute ----------------

// UaCT[d][a] = UaC_w[a][d]  (coalesced reads, scattered writes; 1.4MB)
__global__ __launch_bounds__(256) void k_tran(const void* __restrict__ UaC_w,
                                              float* __restrict__ UaCT,
                                              const int* __restrict__ flag){
  const int f32 = flag[0];
  size_t i = (size_t)blockIdx.x*256 + threadIdx.x;
  if (i >= (size_t)512*DD_) return;
  int a = (int)(i / DD_), d = (int)(i - (size_t)a*DD_);
  UaCT[(size_t)d*512 + a] = gld(UaC_w, i, f32);
}

// FKt[tap][a] = sum_c UfC[a,c]*QC[c,tap];  grid 18
__global__ __launch_bounds__(256) void k_fk(const void* __restrict__ QC, const void* __restrict__ UfC,
                                            float* __restrict__ FKt, const int* __restrict__ flag){
  const int f32 = flag[0];
  __shared__ float qc[4608];
  int tid = threadIdx.x;
  for (int k=tid;k<4608;k+=256) qc[k] = gld(QC, k, f32);
  __syncthreads();
  int flat = blockIdx.x*256 + tid;      // < 4608
  int a = flat & 511, tap = flat >> 9;
  float acc = 0.f;
  for (int c=0;c<512;c++) acc = fmaf(gld(UfC, (size_t)a*512 + c, f32), qc[c*9+tap], acc);
  FKt[tap*512 + a] = acc;
}

// pctx[b][p][a] = context[b,:,p].UaC[a,:] + UaC_b[a] + UfC_b[a]
// grid 144 = 8b x 18 ptiles(32), block 512 (thread = a), FMA-bound (~40us)
__global__ __launch_bounds__(512) void k_pctx2(const void* __restrict__ context,
    const float* __restrict__ UaCT, const void* __restrict__ UaC_b, const void* __restrict__ UfC_b,
    float* __restrict__ pctx, const int* __restrict__ flag){
  const int f32 = flag[0];
  const int blk = blockIdx.x;
  const int b = blk / 18;
  const int pbase = (blk - b*18) * 32;
  __shared__ float ctx[32][DD_];   // 87.5 KB
  const int tid = threadIdx.x;
  for (int k=tid; k<32*DD_; k+=512){
    int p = k & 31, d = k >> 5;
    ctx[p][d] = gld(context, ((size_t)(b*DD_+d))*PP_ + pbase + p, f32);
  }
  __syncthreads();
  const int a = tid;
  float acc[32];
  #pragma unroll
  for (int p=0;p<32;p++) acc[p] = 0.f;
  for (int d=0; d<DD_; d+=4){      // 684 = 171*4
    float w0 = UaCT[(size_t)(d+0)*512 + a];
    float w1 = UaCT[(size_t)(d+1)*512 + a];
    float w2 = UaCT[(size_t)(d+2)*512 + a];
    float w3 = UaCT[(size_t)(d+3)*512 + a];
    #pragma unroll
    for (int p=0;p<32;p++){
      float4 c = *(const float4*)(&ctx[p][d]);
      float t = acc[p];
      t = fmaf(c.x, w0, t); t = fmaf(c.y, w1, t);
      t = fmaf(c.z, w2, t); t = fmaf(c.w, w3, t);
      acc[p] = t;
    }
  }
  float bias = gld(UaC_b, a, f32) + gld(UfC_b, a, f32);
  #pragma unroll
  for (int p=0;p<32;p++)
    pctx[((size_t)(b*PP_ + pbase + p))*512 + a] = acc[p] + bias;
}

// sb[g][t][b][n];  grid 768 = 3*32*8, thread = n
__global__ __launch_bounds__(256) void k_sb(const void* __restrict__ remb, const void* __restrict__ re_emb,
    const void* __restrict__ Wz, const void* __restrict__ bz,
    const void* __restrict__ Wr, const void* __restrict__ br,
    const void* __restrict__ Wh, const void* __restrict__ bhh,
    float* __restrict__ sb, const int* __restrict__ flag){
  const int f32 = flag[0];
  int blk = blockIdx.x;
  int g = blk >> 8;
  int tb = blk & 255; int t = tb >> 3; int b = tb & 7;
  __shared__ float emb[512];
  int tid = threadIdx.x;
  emb[tid]     = gld(remb,   (size_t)(t*8+b)*256 + tid, f32);
  emb[tid+256] = gld(re_emb, (size_t)(t*8+b)*256 + tid, f32);
  __syncthreads();
  const void* W = (g==0?Wz:(g==1?Wr:Wh));
  const void* bias = (g==0?bz:(g==1?br:bhh));
  float acc = gld(bias, tid, f32) + dotw(W, (size_t)tid*512, emb, 512, f32);
  sb[(((size_t)g*32+t)*8+b)*256 + tid] = acc;
}

// ---------------- persistent main: grid 8 (1 block per b), block 576, loop t inside ----------------
__global__ __launch_bounds__(576, 1) void k_main(
    const void* __restrict__ ly_mask, const void* __restrict__ context, const void* __restrict__ cmask,
    const void* __restrict__ init_state,
    const void* __restrict__ Uhz0, const void* __restrict__ Uhr0, const void* __restrict__ Uhh0,
    const void* __restrict__ WaC, const void* __restrict__ vaC_w, const void* __restrict__ vaC_b,
    const void* __restrict__ Uhz2, const void* __restrict__ Uhz2_b,
    const void* __restrict__ Uhr2, const void* __restrict__ Uhr2_b,
    const void* __restrict__ Uhh2, const void* __restrict__ Uhh2_b,
    const void* __restrict__ Wcz, const void* __restrict__ Wcr, const void* __restrict__ Wch,
    const int* __restrict__ rp,
    const float* __restrict__ pctx, const float* __restrict__ sb, const float* __restrict__ FKt,
    float* __restrict__ buf, float* __restrict__ out, const int* __restrict__ flag)
{
  const int f32 = flag[0];
  const int b = blockIdx.x;
  const int tid = threadIdx.x;

  __shared__ float h_s[NN_], h0_s[NN_], q_s[512];
  __shared__ float ap_s[PP_], al_s[PP_], cm_s[PP_];
  __shared__ float ctc_s[DD_];
  __shared__ float fk_s[9*512], vac_s[512];
  __shared__ float red_s[9];

  // one-time init
  if (tid < 256) h_s[tid] = gld(init_state, b*256 + tid, f32);
  ap_s[tid] = 0.f;
  cm_s[tid] = gld(cmask, b*PP_ + tid, f32);
  for (int k=tid; k<4608; k+=576) fk_s[k] = FKt[k];
  if (tid < 512) vac_s[tid] = gld(vaC_w, tid, f32);
  for (int e=0; e<32; e++)
    for (int d=tid; d<DD_; d+=576) buf[((size_t)e*8 + b)*DD_ + d] = 0.f;
  const float vb = gld(vaC_b, 0, f32);
  const int hh = tid / 48, ww = tid - hh*48;
  __syncthreads();

  for (int t=0; t<32; t++){
    const float lm = gld(ly_mask, t*8+b, f32);

    //---- P1: GRU1 (tid<256) + ctP gather (all threads)
    if (tid < 256){
      int n = tid;
      float az = dotw(Uhz0, (size_t)n*256, h_s, 256, f32);
      float ar = dotw(Uhr0, (size_t)n*256, h_s, 256, f32);
      float ah = dotw(Uhh0, (size_t)n*256, h_s, 256, f32);
      float hp = h_s[n];
      float z0 = sigm(az + sb[(((size_t)t)*8+b)*256 + n]);
      float r0 = sigm(ar + sb[(((size_t)(32+t))*8+b)*256 + n]);
      float hc = tanh_c(ah*r0 + sb[(((size_t)(64+t))*8+b)*256 + n]);
      float h0v = z0*hp + (1.f - z0)*hc;
      h0v = lm*h0v + (1.f - lm)*hp;
      h0_s[n] = h0v;
    }
    {
      int rpos = rp[t*8+b];
      if ((unsigned)rpos > 31u) rpos = 31;
      for (int d=tid; d<DD_; d+=576)
        out[OFF_CTP + (t*8+b)*DD_ + d] = buf[((size_t)rpos*8+b)*DD_ + d];
    }
    __syncthreads();

    //---- P2: query (tid<512)
    if (tid < 512)
      q_s[tid] = dotw(WaC, (size_t)tid*256, h0_s, 256, f32);
    __syncthreads();

    //---- P3: scores + softmax (thread = p)
    {
      float av[9];
      #pragma unroll
      for (int kh=0;kh<3;kh++){
        #pragma unroll
        for (int kw=0;kw<3;kw++){
          int h2v = hh + kh - 1, w2v = ww + kw - 1;
          av[kh*3+kw] = ((unsigned)h2v < 12u && (unsigned)w2v < 48u) ? ap_s[h2v*48 + w2v] : 0.f;
        }
      }
      const float* pc = pctx + ((size_t)(b*PP_ + tid))*512;
      float racc = 0.f;
      for (int a=0; a<512; a+=4){
        float4 u = *(const float4*)(pc + a);
        float s0=u.x, s1=u.y, s2=u.z, s3=u.w;
        #pragma unroll
        for (int tp=0; tp<9; tp++){
          float4 f = *(const float4*)(&fk_s[tp*512 + a]);
          float avv = av[tp];
          s0 = fmaf(avv, f.x, s0); s1 = fmaf(avv, f.y, s1);
          s2 = fmaf(avv, f.z, s2); s3 = fmaf(avv, f.w, s3);
        }
        float4 qv = *(const float4*)(&q_s[a]);
        float4 vv = *(const float4*)(&vac_s[a]);
        racc = fmaf(vv.x, tanh_c(s0 + qv.x), racc);
        racc = fmaf(vv.y, tanh_c(s1 + qv.y), racc);
        racc = fmaf(vv.z, tanh_c(s2 + qv.z), racc);
        racc = fmaf(vv.w, tanh_c(s3 + qv.w), racc);
      }
      float raw = fminf(fmaxf(racc + vb, -60.f), 60.f);
      float e = __expf(raw) * cm_s[tid];
      al_s[tid] = e;
      float psum = e;
      #pragma unroll
      for (int off=1; off<64; off<<=1) psum += __shfl_xor(psum, off, 64);
      if ((tid & 63) == 0) red_s[tid >> 6] = psum;
    }
    __syncthreads();
    {
      float S = 0.f;
      #pragma unroll
      for (int w=0; w<9; w++) S += red_s[w];
      S = fmaxf(S, 1e-30f);
      float inv = rcpf(S);
      float af = al_s[tid]*inv + 1e-10f;
      al_s[tid] = af;
      out[OFF_AL + (t*8+b)*PP_ + tid] = af;
      float apn = ap_s[tid] + af;
      ap_s[tid] = apn;
      out[OFF_APO + (t*8+b)*PP_ + tid] = apn;
    }
    __syncthreads();

    //---- P4: ctC
    for (int d=tid; d<DD_; d+=576){
      float acc;
      if (f32) acc = dotf((const float*)context + ((size_t)(b*DD_+d))*PP_, al_s, PP_);
      else {
        const u16* crow = (const u16*)context + ((size_t)(b*DD_+d))*PP_;
        acc = 0.f;
        #pragma unroll 8
        for (int k=0;k<PP_;k+=8) acc += dot8(*(const uint4*)(crow+k), &al_s[k]);
      }
      ctc_s[d] = acc;
      if (t < 31) buf[(((size_t)(t+1))*8+b)*DD_ + d] = acc;
      out[OFF_CTC + (t*8+b)*DD_ + d] = acc;
    }
    __syncthreads();

    //---- P5: GRU2 -> h
    if (tid < 256){
      int n = tid;
      float az = dotw(Uhz2, (size_t)n*256, h0_s, 256, f32);
      float ar = dotw(Uhr2, (size_t)n*256, h0_s, 256, f32);
      float ah = dotw(Uhh2, (size_t)n*256, h0_s, 256, f32);
      float cz = dotw(Wcz, (size_t)n*DD_, ctc_s, DD_, f32);
      float cr = dotw(Wcr, (size_t)n*DD_, ctc_s, DD_, f32);
      float ch = dotw(Wch, (size_t)n*DD_, ctc_s, DD_, f32);
      float h0v = h0_s[n];
      float z2 = sigm(az + gld(Uhz2_b, n, f32) + cz);
      float r2 = sigm(ar + gld(Uhr2_b, n, f32) + cr);
      float hc = tanh_c((ah + gld(Uhh2_b, n, f32))*r2 + ch);
      float h2v = z2*h0v + (1.f - z2)*hc;
      h2v = lm*h2v + (1.f - lm)*h0v;
      h_s[n] = h2v;
      out[OFF_H2 + (t*8+b)*256 + n] = h2v;
    }
    __syncthreads();
  }
}

// ---------------- host ----------------

extern "C" void kernel_launch(void* const* d_in, const int* in_sizes, int n_in,
                              void* d_out, int out_size, void* d_ws, size_t ws_size,
                              hipStream_t stream){
  (void)in_sizes; (void)n_in; (void)out_size;
  if (ws_size < WS_NEED) return;   // constant per-deployment; same behavior every call

  const void* remb       = d_in[0];
  const void* re_emb     = d_in[1];
  const void* ly_mask    = d_in[2];
  const void* context    = d_in[3];
  const void* cmask      = d_in[4];
  const void* init_state = d_in[5];
  const void* Wyz_w = d_in[6];  const void* Wyz_b = d_in[7];
  const void* Wyr_w = d_in[8];  const void* Wyr_b = d_in[9];
  const void* Wyh_w = d_in[10]; const void* Wyh_b = d_in[11];
  const void* Uhz0  = d_in[12];
  const void* Uhr0  = d_in[13];
  const void* Uhh0  = d_in[14];
  const void* UaC_w = d_in[15]; const void* UaC_b = d_in[16];
  const void* WaC_w = d_in[17];
  const void* QC_w  = d_in[18];
  const void* UfC_w = d_in[19]; const void* UfC_b = d_in[20];
  const void* vaC_w = d_in[21]; const void* vaC_b = d_in[22];
  const void* Uhz2  = d_in[23]; const void* Uhz2_b = d_in[24];
  const void* Uhr2  = d_in[25]; const void* Uhr2_b = d_in[26];
  const void* Uhh2  = d_in[27]; const void* Uhh2_b = d_in[28];
  const void* Wcz   = d_in[29];
  const void* Wcr   = d_in[30];
  const void* Wch   = d_in[31];
  const int*  rp    = (const int*)d_in[32];

  char* ws = (char*)d_ws;
  float* sbp   = (float*)(ws + OFF_SB);
  float* UaCT  = (float*)(ws + OFF_TRAN);
  float* buf   = (float*)(ws + OFF_BUF);
  float* pctx  = (float*)(ws + OFF_PCTX);
  float* FKt   = (float*)(ws + OFF_FKT);
  int*   flag  = (int*)  (ws + OFF_FLG);
  float* out   = (float*)d_out;

  k_detect<<<1, 256, 0, stream>>>((const u16*)context, flag);
  k_tran <<<1368, 256, 0, stream>>>(UaC_w, UaCT, flag);
  k_fk   <<<18,  256, 0, stream>>>(QC_w, UfC_w, FKt, flag);
  k_pctx2<<<144, 512, 0, stream>>>(context, UaCT, UaC_b, UfC_b, pctx, flag);
  // k_sb overwrites region0 (UaCT dead after k_pctx2)
  k_sb   <<<768, 256, 0, stream>>>(remb, re_emb, Wyz_w, Wyz_b, Wyr_w, Wyr_b, Wyh_w, Wyh_b, sbp, flag);
  k_main <<<8, 576, 0, stream>>>(ly_mask, context, cmask, init_state,
                                 Uhz0, Uhr0, Uhh0, WaC_w, vaC_w, vaC_b,
                                 Uhz2, Uhz2_b, Uhr2, Uhr2_b, Uhh2, Uhh2_b,
                                 Wcz, Wcr, Wch, rp,
                                 pctx, sbp, FKt, buf, out, flag);
}

// Round 9
// 3420.481 us; speedup vs baseline: 2.5992x; 2.5992x over previous
//
#include <hip/hip_runtime.h>
#include <stdint.h>

typedef unsigned short u16;
typedef unsigned int   u32;

// problem dims
#define TB_ 8      // batch
#define NN_ 256    // state n
#define DD_ 684    // context depth d
#define PP_ 576    // H*W = 12*48

// workspace layout (bytes). Region0 [0, 1486848) time-shared:
//   phase1: UaCT (f32 [684][512]) -- k_tran writes, k_pctx2 reads
//   phase2: sb @0 + buf @786432   -- after k_pctx2
#define OFF_SB    0u
#define OFF_TRAN  0u
#define OFF_BUF   786432u
#define OFF_PCTX  1486848u    // f32 [b][p(576)][a(512)]
#define OFF_FKT   10924032u   // f32 [tap(9)][a(512)]
#define OFF_RAWP  10942464u   // f32 [b][j(16)][p(576)]
#define OFF_H     11237376u   // f32 [b][n]
#define OFF_H0    11245568u   // f32 [b][n]
#define OFF_AP    11253760u   // f32 [b][p]
#define OFF_CTR   11272192u   // u32 [b][64]
#define OFF_FLG   11274240u   // int dtype flag
#define WS_NEED   11274256u   // <= 11288592 proven available (R6/R7 ran)

// output offsets (elements, f32)
#define OFF_H2   0
#define OFF_CTC  65536
#define OFF_CTP  240640
#define OFF_AL   415744
#define OFF_APO  563200

__device__ __forceinline__ float b2f(u16 v){ union{u32 i; float f;} x; x.i = ((u32)v)<<16; return x.f; }
__device__ __forceinline__ float gld(const void* p, size_t i, int f32){
  if (f32) return ((const float*)p)[i];
  return b2f(((const u16*)p)[i]);
}
__device__ __forceinline__ float bl(u32 v){ union{u32 i; float f;} x; x.i = v<<16; return x.f; }
__device__ __forceinline__ float bh(u32 v){ union{u32 i; float f;} x; x.i = v & 0xFFFF0000u; return x.f; }

__device__ __forceinline__ float rcpf(float x){ return __builtin_amdgcn_rcpf(x); }
__device__ __forceinline__ float sigm(float x){
  x = fminf(fmaxf(x, -30.f), 30.f);
  return rcpf(1.f + __expf(-x));
}
__device__ __forceinline__ float tanh_c(float x){
  x = fminf(fmaxf(x, -15.f), 15.f);
  float e = __expf(2.f*x);
  return 1.f - 2.f*rcpf(e + 1.f);
}

__device__ __forceinline__ float dot8(uint4 u, const float* s){
  float a = fmaf(bl(u.x), s[0], bh(u.x)*s[1]);
  a = fmaf(bl(u.y), s[2], a); a = fmaf(bh(u.y), s[3], a);
  a = fmaf(bl(u.z), s[4], a); a = fmaf(bh(u.z), s[5], a);
  a = fmaf(bl(u.w), s[6], a); a = fmaf(bh(u.w), s[7], a);
  return a;
}
__device__ __forceinline__ float dot4t(uint2 u, const float* s, float a){
  a = fmaf(bl(u.x), s[0], a); a = fmaf(bh(u.x), s[1], a);
  a = fmaf(bl(u.y), s[2], a); a = fmaf(bh(u.y), s[3], a);
  return a;
}
__device__ __forceinline__ float dotf(const float* w, const float* s, int n){
  float a = 0.f;
  #pragma unroll 4
  for (int k=0;k<n;k+=4){
    float4 u = *(const float4*)(w+k);
    a = fmaf(u.x, s[k], a);   a = fmaf(u.y, s[k+1], a);
    a = fmaf(u.z, s[k+2], a); a = fmaf(u.w, s[k+3], a);
  }
  return a;
}
__device__ __forceinline__ float dotw(const void* W, size_t row_off, const float* s, int n, int f32){
  if (f32) return dotf((const float*)W + row_off, s, n);
  const u16* r = (const u16*)W + row_off;
  float a = 0.f;
  int k = 0;
  for (; k+8 <= n; k += 8) a += dot8(*(const uint4*)(r+k), s+k);
  if (k < n) a = dot4t(*(const uint2*)(r+k), s+k, a);
  return a;
}

// ---------------- dtype detector ----------------
__global__ void k_detect(const u16* __restrict__ ctx_u16, int* __restrict__ flag){
  __shared__ int cnt;
  if (threadIdx.x == 0) cnt = 0;
  __syncthreads();
  int bad = 0;
  for (int k = threadIdx.x; k < 512; k += 256){
    u16 v = ctx_u16[k];
    int e = (v >> 7) & 0xFF;
    bool sane = (v == 0u) || (v == 0x8000u) || (e >= 102 && e <= 141);
    if (!sane) bad++;
  }
  atomicAdd(&cnt, bad);
  __syncthreads();
  if (threadIdx.x == 0) flag[0] = (cnt > 64) ? 1 : 0;
}

// ---------------- precompute ----------------

__global__ __launch_bounds__(256) void k_init(float* __restrict__ buf, float* __restrict__ ap,
                                              u32* __restrict__ ctr, float* __restrict__ h,
                                              const void* __restrict__ init_state,
                                              const int* __restrict__ flag){
  const int f32 = flag[0];
  int i = blockIdx.x*blockDim.x + threadIdx.x;
  int stride = gridDim.x*blockDim.x;
  for (int k=i; k<32*TB_*DD_; k+=stride) buf[k] = 0.f;
  for (int k=i; k<TB_*PP_;    k+=stride) ap[k]  = 0.f;
  for (int k=i; k<TB_*64;     k+=stride) ctr[k] = 0u;
  for (int k=i; k<TB_*NN_;    k+=stride) h[k]   = gld(init_state, k, f32);
}

// UaCT[d][a] = UaC_w[a][d]
__global__ __launch_bounds__(256) void k_tran(const void* __restrict__ UaC_w,
                                              float* __restrict__ UaCT,
                                              const int* __restrict__ flag){
  const int f32 = flag[0];
  size_t i = (size_t)blockIdx.x*256 + threadIdx.x;
  if (i >= (size_t)512*DD_) return;
  int a = (int)(i / DD_), d = (int)(i - (size_t)a*DD_);
  UaCT[(size_t)d*512 + a] = gld(UaC_w, i, f32);
}

// FKt[tap][a] = sum_c UfC[a,c]*QC[c,tap]
__global__ __launch_bounds__(256) void k_fk(const void* __restrict__ QC, const void* __restrict__ UfC,
                                            float* __restrict__ FKt, const int* __restrict__ flag){
  const int f32 = flag[0];
  __shared__ float qc[4608];
  int tid = threadIdx.x;
  for (int k=tid;k<4608;k+=256) qc[k] = gld(QC, k, f32);
  __syncthreads();
  int flat = blockIdx.x*256 + tid;
  int a = flat & 511, tap = flat >> 9;
  float acc = 0.f;
  for (int c=0;c<512;c++) acc = fmaf(gld(UfC, (size_t)a*512 + c, f32), qc[c*9+tap], acc);
  FKt[tap*512 + a] = acc;
}

// pctx[b][p][a] = context[b,:,p].UaC[a,:] + UaC_b[a] + UfC_b[a]
__global__ __launch_bounds__(512) void k_pctx2(const void* __restrict__ context,
    const float* __restrict__ UaCT, const void* __restrict__ UaC_b, const void* __restrict__ UfC_b,
    float* __restrict__ pctx, const int* __restrict__ flag){
  const int f32 = flag[0];
  const int blk = blockIdx.x;
  const int b = blk / 18;
  const int pbase = (blk - b*18) * 32;
  __shared__ float ctx[32][DD_];
  const int tid = threadIdx.x;
  for (int k=tid; k<32*DD_; k+=512){
    int p = k & 31, d = k >> 5;
    ctx[p][d] = gld(context, ((size_t)(b*DD_+d))*PP_ + pbase + p, f32);
  }
  __syncthreads();
  const int a = tid;
  float acc[32];
  #pragma unroll
  for (int p=0;p<32;p++) acc[p] = 0.f;
  for (int d=0; d<DD_; d+=4){
    float w0 = UaCT[(size_t)(d+0)*512 + a];
    float w1 = UaCT[(size_t)(d+1)*512 + a];
    float w2 = UaCT[(size_t)(d+2)*512 + a];
    float w3 = UaCT[(size_t)(d+3)*512 + a];
    #pragma unroll
    for (int p=0;p<32;p++){
      float4 c = *(const float4*)(&ctx[p][d]);
      float t = acc[p];
      t = fmaf(c.x, w0, t); t = fmaf(c.y, w1, t);
      t = fmaf(c.z, w2, t); t = fmaf(c.w, w3, t);
      acc[p] = t;
    }
  }
  float bias = gld(UaC_b, a, f32) + gld(UfC_b, a, f32);
  #pragma unroll
  for (int p=0;p<32;p++)
    pctx[((size_t)(b*PP_ + pbase + p))*512 + a] = acc[p] + bias;
}

// sb[g][t][b][n]
__global__ __launch_bounds__(256) void k_sb(const void* __restrict__ remb, const void* __restrict__ re_emb,
    const void* __restrict__ Wz, const void* __restrict__ bz,
    const void* __restrict__ Wr, const void* __restrict__ br,
    const void* __restrict__ Wh, const void* __restrict__ bhh,
    float* __restrict__ sb, const int* __restrict__ flag){
  const int f32 = flag[0];
  int blk = blockIdx.x;
  int g = blk >> 8;
  int tb = blk & 255; int t = tb >> 3; int b = tb & 7;
  __shared__ float emb[512];
  int tid = threadIdx.x;
  emb[tid]     = gld(remb,   (size_t)(t*8+b)*256 + tid, f32);
  emb[tid+256] = gld(re_emb, (size_t)(t*8+b)*256 + tid, f32);
  __syncthreads();
  const void* W = (g==0?Wz:(g==1?Wr:Wh));
  const void* bias = (g==0?bz:(g==1?br:bhh));
  float acc = gld(bias, tid, f32) + dotw(W, (size_t)tid*512, emb, 512, f32);
  sb[(((size_t)g*32+t)*8+b)*256 + tid] = acc;
}

// ---------------- persistent main: 128 blocks = 8 groups(b) x 16 (j); 4 group barriers/step
// Evidence barrier is sound: R3(barrier) and R4(serial chain) produced identical outputs.

__device__ __forceinline__ void group_bar(u32* ctr, u32 target){
  __threadfence();
  __syncthreads();
  if (threadIdx.x == 0){
    __hip_atomic_fetch_add(ctr, 1u, __ATOMIC_ACQ_REL, __HIP_MEMORY_SCOPE_AGENT);
    while (__hip_atomic_load(ctr, __ATOMIC_ACQUIRE, __HIP_MEMORY_SCOPE_AGENT) < target)
      __builtin_amdgcn_s_sleep(4);
  }
  __syncthreads();
  __threadfence();
}

__global__ __launch_bounds__(256, 1) void k_main(
    const void* __restrict__ ly_mask, const void* __restrict__ context, const void* __restrict__ cmask,
    const void* __restrict__ Uhz0, const void* __restrict__ Uhr0, const void* __restrict__ Uhh0,
    const void* __restrict__ WaC, const void* __restrict__ vaC_w, const void* __restrict__ vaC_b,
    const void* __restrict__ Uhz2, const void* __restrict__ Uhz2_b,
    const void* __restrict__ Uhr2, const void* __restrict__ Uhr2_b,
    const void* __restrict__ Uhh2, const void* __restrict__ Uhh2_b,
    const void* __restrict__ Wcz, const void* __restrict__ Wcr, const void* __restrict__ Wch,
    const int* __restrict__ rp,
    const float* __restrict__ pctx, const float* __restrict__ sb, const float* __restrict__ FKt,
    float* buf, float* h_ws, float* h0_ws, float* ap_ws, float* rawp, u32* ctrs,
    float* __restrict__ out, const int* __restrict__ flag)
{
  const int f32 = flag[0];
  const int tid = threadIdx.x;
  const int b = blockIdx.x >> 4;
  const int j = blockIdx.x & 15;
  const int abase = j*32, nbase = j*16;

  __shared__ float hprev[NN_], h0_lds[NN_];
  __shared__ float ap_lds[PP_], al_lds[PP_], cm_lds[PP_];
  __shared__ float ctc_lds[DD_];
  __shared__ float fk_lds[9*32], vac_lds[32], q_lds[32], qpart[256];
  __shared__ float g1[48], u2l[48], wcl[48];
  __shared__ float red[4];

  for (int k=tid; k<288; k+=256) fk_lds[k] = FKt[(k>>5)*512 + abase + (k&31)];
  if (tid < 32) vac_lds[tid] = gld(vaC_w, abase + tid, f32);
  cm_lds[tid]     = gld(cmask, b*PP_ + tid, f32);
  cm_lds[tid+256] = gld(cmask, b*PP_ + tid + 256, f32);
  if (tid < 64) cm_lds[tid+512] = gld(cmask, b*PP_ + tid + 512, f32);
  const float vb = gld(vaC_b, 0, f32);

  u32* ctr = ctrs + b*64;
  u32 bar_t = 0;
  const int p0 = tid, p1 = tid + 256, p2 = tid + 512;
  const bool has3 = (tid < 64);

  for (int t=0; t<32; t++){
    const float lm = gld(ly_mask, t*8+b, f32);

    //---- P1: stage state, GRU1 (n-slice), ctP chunk
    __syncthreads();
    hprev[tid] = h_ws[b*256 + tid];
    ap_lds[p0] = ap_ws[b*PP_ + p0];
    ap_lds[p1] = ap_ws[b*PP_ + p1];
    if (has3) ap_lds[p2] = ap_ws[b*PP_ + p2];
    __syncthreads();

    if (tid < 192){
      int item = tid >> 2, q = tid & 3;
      int g = item >> 4, nl = item & 15;
      int n = nbase + nl;
      const void* U = (g==0 ? Uhz0 : (g==1 ? Uhr0 : Uhh0));
      float acc = dotw(U, (size_t)n*256 + q*64, &hprev[q*64], 64, f32);
      acc += __shfl_xor(acc,1,64); acc += __shfl_xor(acc,2,64);
      if (q==0) g1[g*16+nl] = acc;
    }
    __syncthreads();
    if (tid < 16){
      int n = nbase + tid;
      float hp = hprev[n];
      float z0 = sigm(g1[tid]    + sb[(((size_t)t)*8+b)*256 + n]);
      float r0 = sigm(g1[16+tid] + sb[(((size_t)(32+t))*8+b)*256 + n]);
      float hc = tanh_c(g1[32+tid]*r0 + sb[(((size_t)(64+t))*8+b)*256 + n]);
      float h0v = z0*hp + (1.f - z0)*hc;
      h0v = lm*h0v + (1.f - lm)*hp;
      h0_ws[b*256 + n] = h0v;
    }
    {
      int rpos = rp[t*8+b];
      if ((unsigned)rpos > 31u) rpos = 31;
      int dbase = j*43, dcnt = (j==15) ? 39 : 43;
      if (tid < dcnt){
        int d = dbase + tid;
        out[OFF_CTP + (t*8+b)*DD_ + d] = buf[((size_t)rpos*8+b)*DD_ + d];
      }
    }
    bar_t += 16; group_bar(ctr, bar_t);   // B1: h0 complete

    //---- P2: query a-slice + scores
    h0_lds[tid] = h0_ws[b*256 + tid];
    __syncthreads();
    {
      int ai = tid & 31, nb = tid >> 5;
      qpart[nb*32 + ai] = dotw(WaC, (size_t)(abase+ai)*256 + nb*32, &h0_lds[nb*32], 32, f32);
    }
    __syncthreads();
    if (tid < 32){
      float qv = 0.f;
      #pragma unroll
      for (int nb2=0;nb2<8;nb2++) qv += qpart[nb2*32 + tid];
      q_lds[tid] = qv;
    }
    __syncthreads();
    for (int rep=0; rep<3; rep++){
      int p = tid + rep*256;
      if (p >= PP_) break;
      float PQ[32];
      const float* pc = pctx + ((size_t)(b*PP_ + p))*512 + abase;
      #pragma unroll
      for (int q8=0;q8<8;q8++){
        float4 u = *(const float4*)(pc + q8*4);
        PQ[q8*4+0]=u.x; PQ[q8*4+1]=u.y; PQ[q8*4+2]=u.z; PQ[q8*4+3]=u.w;
      }
      int hh_ = p / 48, ww_ = p - hh_*48;
      #pragma unroll
      for (int kh=0;kh<3;kh++){
        int h2_ = hh_ + kh - 1;
        if ((unsigned)h2_ >= 12u) continue;
        #pragma unroll
        for (int kw=0;kw<3;kw++){
          int w2_ = ww_ + kw - 1;
          if ((unsigned)w2_ >= 48u) continue;
          float av = ap_lds[h2_*48 + w2_];
          const float* fkp = &fk_lds[(kh*3+kw)*32];
          #pragma unroll
          for (int ai=0;ai<32;ai++) PQ[ai] = fmaf(av, fkp[ai], PQ[ai]);
        }
      }
      float racc = 0.f;
      #pragma unroll
      for (int ai=0;ai<32;ai++)
        racc = fmaf(vac_lds[ai], tanh_c(PQ[ai] + q_lds[ai]), racc);
      rawp[((size_t)(b*16+j))*PP_ + p] = racc;
    }
    bar_t += 16; group_bar(ctr, bar_t);   // B2: raw partials complete

    //---- P3: softmax + outputs + ctC chunk + GRU2 U-dots
    {
      float psum = 0.f;
      for (int rep=0; rep<3; rep++){
        int p = tid + rep*256;
        if (p >= PP_) break;
        float raw = vb;
        #pragma unroll
        for (int j2=0;j2<16;j2++) raw += rawp[((size_t)(b*16+j2))*PP_ + p];
        raw = fminf(fmaxf(raw, -60.f), 60.f);
        float e = __expf(raw) * cm_lds[p];
        al_lds[p] = e; psum += e;
      }
      #pragma unroll
      for (int off=1; off<64; off<<=1) psum += __shfl_xor(psum, off, 64);
      if ((tid & 63)==0) red[tid>>6] = psum;
    }
    __syncthreads();
    {
      float S = red[0] + red[1] + red[2] + red[3];
      S = fmaxf(S, 1e-30f);
      float inv = rcpf(S);
      al_lds[p0] = al_lds[p0]*inv + 1e-10f;
      al_lds[p1] = al_lds[p1]*inv + 1e-10f;
      if (has3) al_lds[p2] = al_lds[p2]*inv + 1e-10f;
    }
    __syncthreads();
    {
      int pb = j*36;
      if (tid < 36){
        int p = pb + tid;
        float af = al_lds[p];
        out[OFF_AL + (t*8+b)*PP_ + p] = af;
        float apn = ap_lds[p] + af;
        ap_ws[b*PP_ + p] = apn;
        out[OFF_APO + (t*8+b)*PP_ + p] = apn;
      }
    }
    {
      int dbase = j*43, dcnt = (j==15) ? 39 : 43;
      if (tid < dcnt*4){
        int dd = tid >> 2, q = tid & 3, d = dbase + dd;
        float acc;
        if (f32) acc = dotf((const float*)context + ((size_t)(b*DD_+d))*PP_ + q*144, &al_lds[q*144], 144);
        else {
          const u16* crow = (const u16*)context + ((size_t)(b*DD_+d))*PP_ + q*144;
          acc = 0.f;
          #pragma unroll 6
          for (int k=0;k<144;k+=8) acc += dot8(*(const uint4*)(crow+k), &al_lds[q*144+k]);
        }
        acc += __shfl_xor(acc,1,64); acc += __shfl_xor(acc,2,64);
        if (q==0){
          buf[(((size_t)(t+1))*8+b)*DD_ + d] = acc;
          out[OFF_CTC + (t*8+b)*DD_ + d] = acc;
        }
      }
    }
    if (tid < 192){
      int item = tid >> 2, q = tid & 3;
      int g = item >> 4, nl = item & 15;
      int n = nbase + nl;
      const void* U = (g==0 ? Uhz2 : (g==1 ? Uhr2 : Uhh2));
      float acc = dotw(U, (size_t)n*256 + q*64, &h0_lds[q*64], 64, f32);
      acc += __shfl_xor(acc,1,64); acc += __shfl_xor(acc,2,64);
      if (q==0) u2l[g*16+nl] = acc;
    }
    bar_t += 16; group_bar(ctr, bar_t);   // B3: ctC complete

    //---- P4: GRU2 combine -> h2
    for (int k=tid; k<DD_; k+=256) ctc_lds[k] = buf[(((size_t)(t+1))*8+b)*DD_ + k];
    __syncthreads();
    if (tid < 192){
      int item = tid >> 2, q = tid & 3;
      int g = item >> 4, nl = item & 15;
      int n = nbase + nl;
      const void* W = (g==0 ? Wcz : (g==1 ? Wcr : Wch));
      int base = q*176, cnt = (q==3) ? 156 : 176;
      float acc = dotw(W, (size_t)n*DD_ + base, &ctc_lds[base], cnt, f32);
      acc += __shfl_xor(acc,1,64); acc += __shfl_xor(acc,2,64);
      if (q==0) wcl[g*16+nl] = acc;
    }
    __syncthreads();
    if (tid < 16){
      int n = nbase + tid;
      float h0v = h0_lds[n];
      float z2 = sigm(u2l[tid]    + gld(Uhz2_b, n, f32) + wcl[tid]);
      float r2 = sigm(u2l[16+tid] + gld(Uhr2_b, n, f32) + wcl[16+tid]);
      float hc = tanh_c((u2l[32+tid] + gld(Uhh2_b, n, f32))*r2 + wcl[32+tid]);
      float h2v = z2*h0v + (1.f - z2)*hc;
      h2v = lm*h2v + (1.f - lm)*h0v;
      h_ws[b*256 + n] = h2v;
      out[OFF_H2 + (t*8+b)*256 + n] = h2v;
    }
    bar_t += 16; group_bar(ctr, bar_t);   // B4: h2 complete
  }
}

// ---------------- host ----------------

extern "C" void kernel_launch(void* const* d_in, const int* in_sizes, int n_in,
                              void* d_out, int out_size, void* d_ws, size_t ws_size,
                              hipStream_t stream){
  (void)in_sizes; (void)n_in; (void)out_size;
  if (ws_size < WS_NEED) return;

  const void* remb       = d_in[0];
  const void* re_emb     = d_in[1];
  const void* ly_mask    = d_in[2];
  const void* context    = d_in[3];
  const void* cmask      = d_in[4];
  const void* init_state = d_in[5];
  const void* Wyz_w = d_in[6];  const void* Wyz_b = d_in[7];
  const void* Wyr_w = d_in[8];  const void* Wyr_b = d_in[9];
  const void* Wyh_w = d_in[10]; const void* Wyh_b = d_in[11];
  const void* Uhz0  = d_in[12];
  const void* Uhr0  = d_in[13];
  const void* Uhh0  = d_in[14];
  const void* UaC_w = d_in[15]; const void* UaC_b = d_in[16];
  const void* WaC_w = d_in[17];
  const void* QC_w  = d_in[18];
  const void* UfC_w = d_in[19]; const void* UfC_b = d_in[20];
  const void* vaC_w = d_in[21]; const void* vaC_b = d_in[22];
  const void* Uhz2  = d_in[23]; const void* Uhz2_b = d_in[24];
  const void* Uhr2  = d_in[25]; const void* Uhr2_b = d_in[26];
  const void* Uhh2  = d_in[27]; const void* Uhh2_b = d_in[28];
  const void* Wcz   = d_in[29];
  const void* Wcr   = d_in[30];
  const void* Wch   = d_in[31];
  const int*  rp    = (const int*)d_in[32];

  char* ws = (char*)d_ws;
  float* sbp   = (float*)(ws + OFF_SB);
  float* UaCT  = (float*)(ws + OFF_TRAN);
  float* buf   = (float*)(ws + OFF_BUF);
  float* pctx  = (float*)(ws + OFF_PCTX);
  float* FKt   = (float*)(ws + OFF_FKT);
  float* rawp  = (float*)(ws + OFF_RAWP);
  float* h_ws  = (float*)(ws + OFF_H);
  float* h0_ws = (float*)(ws + OFF_H0);
  float* ap_ws = (float*)(ws + OFF_AP);
  u32*   ctrs  = (u32*)  (ws + OFF_CTR);
  int*   flag  = (int*)  (ws + OFF_FLG);
  float* out   = (float*)d_out;

  k_detect<<<1, 256, 0, stream>>>((const u16*)context, flag);
  k_tran <<<1368, 256, 0, stream>>>(UaC_w, UaCT, flag);
  k_fk   <<<18,  256, 0, stream>>>(QC_w, UfC_w, FKt, flag);
  k_pctx2<<<144, 512, 0, stream>>>(context, UaCT, UaC_b, UfC_b, pctx, flag);
  // region0 reuse: UaCT dead after k_pctx2
  k_sb   <<<768, 256, 0, stream>>>(remb, re_emb, Wyz_w, Wyz_b, Wyr_w, Wyr_b, Wyh_w, Wyh_b, sbp, flag);
  k_init <<<256, 256, 0, stream>>>(buf, ap_ws, ctrs, h_ws, init_state, flag);
  k_main <<<128, 256, 0, stream>>>(ly_mask, context, cmask,
                                   Uhz0, Uhr0, Uhh0, WaC_w, vaC_w, vaC_b,
                                   Uhz2, Uhz2_b, Uhr2, Uhr2_b, Uhh2, Uhh2_b,
                                   Wcz, Wcr, Wch, rp,
                                   pctx, sbp, FKt,
                                   buf, h_ws, h0_ws, ap_ws, rawp, ctrs, out, flag);
}

// Round 10
// 1283.968 us; speedup vs baseline: 6.9243x; 2.6640x over previous
//
#include <hip/hip_runtime.h>
#include <stdint.h>

typedef unsigned short u16;
typedef unsigned int   u32;

// problem dims
#define TB_ 8      // batch
#define NN_ 256    // state n
#define DD_ 684    // context depth d
#define PP_ 576    // H*W = 12*48

// workspace layout (bytes). Region0 [0, 1486848) time-shared:
//   phase1: UaCT (f32 [684][512]) -- k_tran writes, k_pctx2 reads
//   phase2: sb @0 + buf @786432   -- after k_pctx2
#define OFF_SB    0u
#define OFF_TRAN  0u
#define OFF_BUF   786432u
#define OFF_PCTX  1486848u    // f32 [b][p(576)][a(512)]
#define OFF_FKT   10924032u   // f32 [tap(9)][a(512)]
#define OFF_RAWP  10942464u   // f32 [b][j(16)][p(576)]
#define OFF_H     11237376u   // f32 [b][n]
#define OFF_H0    11245568u   // f32 [b][n]
#define OFF_AP    11253760u   // f32 [b][p]
#define OFF_CTR   11272192u   // u32 [b][64]
#define OFF_FLG   11274240u   // int dtype flag
#define WS_NEED   11274256u

// output offsets (elements, f32)
#define OFF_H2   0
#define OFF_CTC  65536
#define OFF_CTP  240640
#define OFF_AL   415744
#define OFF_APO  563200

__device__ __forceinline__ float b2f(u16 v){ union{u32 i; float f;} x; x.i = ((u32)v)<<16; return x.f; }
__device__ __forceinline__ float gld(const void* p, size_t i, int f32){
  if (f32) return ((const float*)p)[i];
  return b2f(((const u16*)p)[i]);
}
__device__ __forceinline__ float bl(u32 v){ union{u32 i; float f;} x; x.i = v<<16; return x.f; }
__device__ __forceinline__ float bh(u32 v){ union{u32 i; float f;} x; x.i = v & 0xFFFF0000u; return x.f; }

// coherence-point (L3) scalar access for cross-block data: no cache flushes needed.
__device__ __forceinline__ float aload(const float* p){
  u32 v = __hip_atomic_load((const u32*)p, __ATOMIC_RELAXED, __HIP_MEMORY_SCOPE_AGENT);
  union{u32 i; float f;} x; x.i = v; return x.f;
}
__device__ __forceinline__ void astore(float* p, float v){
  union{float f; u32 i;} x; x.f = v;
  __hip_atomic_store((u32*)p, x.i, __ATOMIC_RELAXED, __HIP_MEMORY_SCOPE_AGENT);
}

__device__ __forceinline__ float rcpf(float x){ return __builtin_amdgcn_rcpf(x); }
__device__ __forceinline__ float sigm(float x){
  x = fminf(fmaxf(x, -30.f), 30.f);
  return rcpf(1.f + __expf(-x));
}
__device__ __forceinline__ float tanh_c(float x){
  x = fminf(fmaxf(x, -15.f), 15.f);
  float e = __expf(2.f*x);
  return 1.f - 2.f*rcpf(e + 1.f);
}

__device__ __forceinline__ float dot8(uint4 u, const float* s){
  float a = fmaf(bl(u.x), s[0], bh(u.x)*s[1]);
  a = fmaf(bl(u.y), s[2], a); a = fmaf(bh(u.y), s[3], a);
  a = fmaf(bl(u.z), s[4], a); a = fmaf(bh(u.z), s[5], a);
  a = fmaf(bl(u.w), s[6], a); a = fmaf(bh(u.w), s[7], a);
  return a;
}
__device__ __forceinline__ float dot4t(uint2 u, const float* s, float a){
  a = fmaf(bl(u.x), s[0], a); a = fmaf(bh(u.x), s[1], a);
  a = fmaf(bl(u.y), s[2], a); a = fmaf(bh(u.y), s[3], a);
  return a;
}
__device__ __forceinline__ float dotf(const float* w, const float* s, int n){
  float a = 0.f;
  #pragma unroll 4
  for (int k=0;k<n;k+=4){
    float4 u = *(const float4*)(w+k);
    a = fmaf(u.x, s[k], a);   a = fmaf(u.y, s[k+1], a);
    a = fmaf(u.z, s[k+2], a); a = fmaf(u.w, s[k+3], a);
  }
  return a;
}
__device__ __forceinline__ float dotw(const void* W, size_t row_off, const float* s, int n, int f32){
  if (f32) return dotf((const float*)W + row_off, s, n);
  const u16* r = (const u16*)W + row_off;
  float a = 0.f;
  int k = 0;
  for (; k+8 <= n; k += 8) a += dot8(*(const uint4*)(r+k), s+k);
  if (k < n) a = dot4t(*(const uint2*)(r+k), s+k, a);
  return a;
}

// ---------------- dtype detector ----------------
__global__ void k_detect(const u16* __restrict__ ctx_u16, int* __restrict__ flag){
  __shared__ int cnt;
  if (threadIdx.x == 0) cnt = 0;
  __syncthreads();
  int bad = 0;
  for (int k = threadIdx.x; k < 512; k += 256){
    u16 v = ctx_u16[k];
    int e = (v >> 7) & 0xFF;
    bool sane = (v == 0u) || (v == 0x8000u) || (e >= 102 && e <= 141);
    if (!sane) bad++;
  }
  atomicAdd(&cnt, bad);
  __syncthreads();
  if (threadIdx.x == 0) flag[0] = (cnt > 64) ? 1 : 0;
}

// ---------------- precompute ----------------

__global__ __launch_bounds__(256) void k_init(float* __restrict__ buf, float* __restrict__ ap,
                                              u32* __restrict__ ctr, float* __restrict__ h,
                                              const void* __restrict__ init_state,
                                              const int* __restrict__ flag){
  const int f32 = flag[0];
  int i = blockIdx.x*blockDim.x + threadIdx.x;
  int stride = gridDim.x*blockDim.x;
  for (int k=i; k<32*TB_*DD_; k+=stride) buf[k] = 0.f;
  for (int k=i; k<TB_*PP_;    k+=stride) ap[k]  = 0.f;
  for (int k=i; k<TB_*64;     k+=stride) ctr[k] = 0u;
  for (int k=i; k<TB_*NN_;    k+=stride) h[k]   = gld(init_state, k, f32);
}

// UaCT[d][a] = UaC_w[a][d]
__global__ __launch_bounds__(256) void k_tran(const void* __restrict__ UaC_w,
                                              float* __restrict__ UaCT,
                                              const int* __restrict__ flag){
  const int f32 = flag[0];
  size_t i = (size_t)blockIdx.x*256 + threadIdx.x;
  if (i >= (size_t)512*DD_) return;
  int a = (int)(i / DD_), d = (int)(i - (size_t)a*DD_);
  UaCT[(size_t)d*512 + a] = gld(UaC_w, i, f32);
}

// FKt[tap][a] = sum_c UfC[a,c]*QC[c,tap]
__global__ __launch_bounds__(256) void k_fk(const void* __restrict__ QC, const void* __restrict__ UfC,
                                            float* __restrict__ FKt, const int* __restrict__ flag){
  const int f32 = flag[0];
  __shared__ float qc[4608];
  int tid = threadIdx.x;
  for (int k=tid;k<4608;k+=256) qc[k] = gld(QC, k, f32);
  __syncthreads();
  int flat = blockIdx.x*256 + tid;
  int a = flat & 511, tap = flat >> 9;
  float acc = 0.f;
  for (int c=0;c<512;c++) acc = fmaf(gld(UfC, (size_t)a*512 + c, f32), qc[c*9+tap], acc);
  FKt[tap*512 + a] = acc;
}

// pctx[b][p][a] = context[b,:,p].UaC[a,:] + UaC_b[a] + UfC_b[a]
__global__ __launch_bounds__(512) void k_pctx2(const void* __restrict__ context,
    const float* __restrict__ UaCT, const void* __restrict__ UaC_b, const void* __restrict__ UfC_b,
    float* __restrict__ pctx, const int* __restrict__ flag){
  const int f32 = flag[0];
  const int blk = blockIdx.x;
  const int b = blk / 18;
  const int pbase = (blk - b*18) * 32;
  __shared__ float ctx[32][DD_];
  const int tid = threadIdx.x;
  for (int k=tid; k<32*DD_; k+=512){
    int p = k & 31, d = k >> 5;
    ctx[p][d] = gld(context, ((size_t)(b*DD_+d))*PP_ + pbase + p, f32);
  }
  __syncthreads();
  const int a = tid;
  float acc[32];
  #pragma unroll
  for (int p=0;p<32;p++) acc[p] = 0.f;
  for (int d=0; d<DD_; d+=4){
    float w0 = UaCT[(size_t)(d+0)*512 + a];
    float w1 = UaCT[(size_t)(d+1)*512 + a];
    float w2 = UaCT[(size_t)(d+2)*512 + a];
    float w3 = UaCT[(size_t)(d+3)*512 + a];
    #pragma unroll
    for (int p=0;p<32;p++){
      float4 c = *(const float4*)(&ctx[p][d]);
      float t = acc[p];
      t = fmaf(c.x, w0, t); t = fmaf(c.y, w1, t);
      t = fmaf(c.z, w2, t); t = fmaf(c.w, w3, t);
      acc[p] = t;
    }
  }
  float bias = gld(UaC_b, a, f32) + gld(UfC_b, a, f32);
  #pragma unroll
  for (int p=0;p<32;p++)
    pctx[((size_t)(b*PP_ + pbase + p))*512 + a] = acc[p] + bias;
}

// sb[g][t][b][n]
__global__ __launch_bounds__(256) void k_sb(const void* __restrict__ remb, const void* __restrict__ re_emb,
    const void* __restrict__ Wz, const void* __restrict__ bz,
    const void* __restrict__ Wr, const void* __restrict__ br,
    const void* __restrict__ Wh, const void* __restrict__ bhh,
    float* __restrict__ sb, const int* __restrict__ flag){
  const int f32 = flag[0];
  int blk = blockIdx.x;
  int g = blk >> 8;
  int tb = blk & 255; int t = tb >> 3; int b = tb & 7;
  __shared__ float emb[512];
  int tid = threadIdx.x;
  emb[tid]     = gld(remb,   (size_t)(t*8+b)*256 + tid, f32);
  emb[tid+256] = gld(re_emb, (size_t)(t*8+b)*256 + tid, f32);
  __syncthreads();
  const void* W = (g==0?Wz:(g==1?Wr:Wh));
  const void* bias = (g==0?bz:(g==1?br:bhh));
  float acc = gld(bias, tid, f32) + dotw(W, (size_t)tid*512, emb, 512, f32);
  sb[(((size_t)g*32+t)*8+b)*256 + tid] = acc;
}

// ---------------- persistent main: 128 blocks = 8 groups(b) x 16 (j); 4 barriers/step
// NO threadfences: __syncthreads() drains vmem (compiler emits waitcnt before s_barrier),
// and all cross-block data goes through agent-scope atomics (coherence point = L3),
// so per-XCD L2 stays hot with read-only weights. Data plane validated in R3 (==R4 output).

__device__ __forceinline__ void group_bar(u32* ctr, u32 target){
  __syncthreads();   // all waves arrived; their vmem (incl. agent atomics) drained
  if (threadIdx.x == 0){
    __hip_atomic_fetch_add(ctr, 1u, __ATOMIC_RELAXED, __HIP_MEMORY_SCOPE_AGENT);
    while (__hip_atomic_load(ctr, __ATOMIC_RELAXED, __HIP_MEMORY_SCOPE_AGENT) < target)
      __builtin_amdgcn_s_sleep(2);
  }
  __syncthreads();   // hw + compiler barrier: subsequent loads can't hoist above
}

__global__ __launch_bounds__(256, 1) void k_main(
    const void* __restrict__ ly_mask, const void* __restrict__ context, const void* __restrict__ cmask,
    const void* __restrict__ Uhz0, const void* __restrict__ Uhr0, const void* __restrict__ Uhh0,
    const void* __restrict__ WaC, const void* __restrict__ vaC_w, const void* __restrict__ vaC_b,
    const void* __restrict__ Uhz2, const void* __restrict__ Uhz2_b,
    const void* __restrict__ Uhr2, const void* __restrict__ Uhr2_b,
    const void* __restrict__ Uhh2, const void* __restrict__ Uhh2_b,
    const void* __restrict__ Wcz, const void* __restrict__ Wcr, const void* __restrict__ Wch,
    const int* __restrict__ rp,
    const float* __restrict__ pctx, const float* __restrict__ sb, const float* __restrict__ FKt,
    float* buf, float* h_ws, float* h0_ws, float* ap_ws, float* rawp, u32* ctrs,
    float* __restrict__ out, const int* __restrict__ flag)
{
  const int f32 = flag[0];
  const int tid = threadIdx.x;
  const int b = blockIdx.x >> 4;
  const int j = blockIdx.x & 15;
  const int abase = j*32, nbase = j*16;

  __shared__ float hprev[NN_], h0_lds[NN_];
  __shared__ float ap_lds[PP_], al_lds[PP_], cm_lds[PP_];
  __shared__ float ctc_lds[DD_];
  __shared__ float fk_lds[9*32], vac_lds[32], q_lds[32], qpart[256];
  __shared__ float g1[48], u2l[48], wcl[48];
  __shared__ float red[4];

  for (int k=tid; k<288; k+=256) fk_lds[k] = FKt[(k>>5)*512 + abase + (k&31)];
  if (tid < 32) vac_lds[tid] = gld(vaC_w, abase + tid, f32);
  cm_lds[tid]     = gld(cmask, b*PP_ + tid, f32);
  cm_lds[tid+256] = gld(cmask, b*PP_ + tid + 256, f32);
  if (tid < 64) cm_lds[tid+512] = gld(cmask, b*PP_ + tid + 512, f32);
  const float vb = gld(vaC_b, 0, f32);

  u32* ctr = ctrs + b*64;
  u32 bar_t = 0;
  const int p0 = tid, p1 = tid + 256, p2 = tid + 512;
  const bool has3 = (tid < 64);

  for (int t=0; t<32; t++){
    const float lm = gld(ly_mask, t*8+b, f32);

    //---- P1: stage state, GRU1 (n-slice), ctP chunk
    __syncthreads();
    hprev[tid] = aload(&h_ws[b*256 + tid]);
    ap_lds[p0] = aload(&ap_ws[b*PP_ + p0]);
    ap_lds[p1] = aload(&ap_ws[b*PP_ + p1]);
    if (has3) ap_lds[p2] = aload(&ap_ws[b*PP_ + p2]);
    __syncthreads();

    if (tid < 192){
      int item = tid >> 2, q = tid & 3;
      int g = item >> 4, nl = item & 15;
      int n = nbase + nl;
      const void* U = (g==0 ? Uhz0 : (g==1 ? Uhr0 : Uhh0));
      float acc = dotw(U, (size_t)n*256 + q*64, &hprev[q*64], 64, f32);
      acc += __shfl_xor(acc,1,64); acc += __shfl_xor(acc,2,64);
      if (q==0) g1[g*16+nl] = acc;
    }
    __syncthreads();
    if (tid < 16){
      int n = nbase + tid;
      float hp = hprev[n];
      float z0 = sigm(g1[tid]    + sb[(((size_t)t)*8+b)*256 + n]);
      float r0 = sigm(g1[16+tid] + sb[(((size_t)(32+t))*8+b)*256 + n]);
      float hc = tanh_c(g1[32+tid]*r0 + sb[(((size_t)(64+t))*8+b)*256 + n]);
      float h0v = z0*hp + (1.f - z0)*hc;
      h0v = lm*h0v + (1.f - lm)*hp;
      astore(&h0_ws[b*256 + n], h0v);
    }
    {
      int rpos = rp[t*8+b];
      if ((unsigned)rpos > 31u) rpos = 31;
      int dbase = j*43, dcnt = (j==15) ? 39 : 43;
      if (tid < dcnt){
        int d = dbase + tid;
        out[OFF_CTP + (t*8+b)*DD_ + d] = aload(&buf[((size_t)rpos*8+b)*DD_ + d]);
      }
    }
    bar_t += 16; group_bar(ctr, bar_t);   // B1: h0 complete

    //---- P2: query a-slice + scores
    h0_lds[tid] = aload(&h0_ws[b*256 + tid]);
    __syncthreads();
    {
      int ai = tid & 31, nb = tid >> 5;
      qpart[nb*32 + ai] = dotw(WaC, (size_t)(abase+ai)*256 + nb*32, &h0_lds[nb*32], 32, f32);
    }
    __syncthreads();
    if (tid < 32){
      float qv = 0.f;
      #pragma unroll
      for (int nb2=0;nb2<8;nb2++) qv += qpart[nb2*32 + tid];
      q_lds[tid] = qv;
    }
    __syncthreads();
    for (int rep=0; rep<3; rep++){
      int p = tid + rep*256;
      if (p >= PP_) break;
      float PQ[32];
      const float* pc = pctx + ((size_t)(b*PP_ + p))*512 + abase;
      #pragma unroll
      for (int q8=0;q8<8;q8++){
        float4 u = *(const float4*)(pc + q8*4);
        PQ[q8*4+0]=u.x; PQ[q8*4+1]=u.y; PQ[q8*4+2]=u.z; PQ[q8*4+3]=u.w;
      }
      int hh_ = p / 48, ww_ = p - hh_*48;
      #pragma unroll
      for (int kh=0;kh<3;kh++){
        int h2_ = hh_ + kh - 1;
        if ((unsigned)h2_ >= 12u) continue;
        #pragma unroll
        for (int kw=0;kw<3;kw++){
          int w2_ = ww_ + kw - 1;
          if ((unsigned)w2_ >= 48u) continue;
          float av = ap_lds[h2_*48 + w2_];
          const float* fkp = &fk_lds[(kh*3+kw)*32];
          #pragma unroll
          for (int ai=0;ai<32;ai++) PQ[ai] = fmaf(av, fkp[ai], PQ[ai]);
        }
      }
      float racc = 0.f;
      #pragma unroll
      for (int ai=0;ai<32;ai++)
        racc = fmaf(vac_lds[ai], tanh_c(PQ[ai] + q_lds[ai]), racc);
      astore(&rawp[((size_t)(b*16+j))*PP_ + p], racc);
    }
    bar_t += 16; group_bar(ctr, bar_t);   // B2: raw partials complete

    //---- P3: softmax + outputs + ctC chunk + GRU2 U-dots
    {
      float psum = 0.f;
      for (int rep=0; rep<3; rep++){
        int p = tid + rep*256;
        if (p >= PP_) break;
        float raw = vb;
        #pragma unroll
        for (int j2=0;j2<16;j2++) raw += aload(&rawp[((size_t)(b*16+j2))*PP_ + p]);
        raw = fminf(fmaxf(raw, -60.f), 60.f);
        float e = __expf(raw) * cm_lds[p];
        al_lds[p] = e; psum += e;
      }
      #pragma unroll
      for (int off=1; off<64; off<<=1) psum += __shfl_xor(psum, off, 64);
      if ((tid & 63)==0) red[tid>>6] = psum;
    }
    __syncthreads();
    {
      float S = red[0] + red[1] + red[2] + red[3];
      S = fmaxf(S, 1e-30f);
      float inv = rcpf(S);
      al_lds[p0] = al_lds[p0]*inv + 1e-10f;
      al_lds[p1] = al_lds[p1]*inv + 1e-10f;
      if (has3) al_lds[p2] = al_lds[p2]*inv + 1e-10f;
    }
    __syncthreads();
    {
      int pb = j*36;
      if (tid < 36){
        int p = pb + tid;
        float af = al_lds[p];
        out[OFF_AL + (t*8+b)*PP_ + p] = af;
        float apn = ap_lds[p] + af;
        astore(&ap_ws[b*PP_ + p], apn);
        out[OFF_APO + (t*8+b)*PP_ + p] = apn;
      }
    }
    {
      int dbase = j*43, dcnt = (j==15) ? 39 : 43;
      if (tid < dcnt*4){
        int dd = tid >> 2, q = tid & 3, d = dbase + dd;
        float acc;
        if (f32) acc = dotf((const float*)context + ((size_t)(b*DD_+d))*PP_ + q*144, &al_lds[q*144], 144);
        else {
          const u16* crow = (const u16*)context + ((size_t)(b*DD_+d))*PP_ + q*144;
          acc = 0.f;
          #pragma unroll 6
          for (int k=0;k<144;k+=8) acc += dot8(*(const uint4*)(crow+k), &al_lds[q*144+k]);
        }
        acc += __shfl_xor(acc,1,64); acc += __shfl_xor(acc,2,64);
        if (q==0){
          astore(&buf[(((size_t)(t+1))*8+b)*DD_ + d], acc);
          out[OFF_CTC + (t*8+b)*DD_ + d] = acc;
        }
      }
    }
    if (tid < 192){
      int item = tid >> 2, q = tid & 3;
      int g = item >> 4, nl = item & 15;
      int n = nbase + nl;
      const void* U = (g==0 ? Uhz2 : (g==1 ? Uhr2 : Uhh2));
      float acc = dotw(U, (size_t)n*256 + q*64, &h0_lds[q*64], 64, f32);
      acc += __shfl_xor(acc,1,64); acc += __shfl_xor(acc,2,64);
      if (q==0) u2l[g*16+nl] = acc;
    }
    bar_t += 16; group_bar(ctr, bar_t);   // B3: ctC complete

    //---- P4: GRU2 combine -> h2
    for (int k=tid; k<DD_; k+=256) ctc_lds[k] = aload(&buf[(((size_t)(t+1))*8+b)*DD_ + k]);
    __syncthreads();
    if (tid < 192){
      int item = tid >> 2, q = tid & 3;
      int g = item >> 4, nl = item & 15;
      int n = nbase + nl;
      const void* W = (g==0 ? Wcz : (g==1 ? Wcr : Wch));
      int base = q*176, cnt = (q==3) ? 156 : 176;
      float acc = dotw(W, (size_t)n*DD_ + base, &ctc_lds[base], cnt, f32);
      acc += __shfl_xor(acc,1,64); acc += __shfl_xor(acc,2,64);
      if (q==0) wcl[g*16+nl] = acc;
    }
    __syncthreads();
    if (tid < 16){
      int n = nbase + tid;
      float h0v = h0_lds[n];
      float z2 = sigm(u2l[tid]    + gld(Uhz2_b, n, f32) + wcl[tid]);
      float r2 = sigm(u2l[16+tid] + gld(Uhr2_b, n, f32) + wcl[16+tid]);
      float hc = tanh_c((u2l[32+tid] + gld(Uhh2_b, n, f32))*r2 + wcl[32+tid]);
      float h2v = z2*h0v + (1.f - z2)*hc;
      h2v = lm*h2v + (1.f - lm)*h0v;
      astore(&h_ws[b*256 + n], h2v);
      out[OFF_H2 + (t*8+b)*256 + n] = h2v;
    }
    bar_t += 16; group_bar(ctr, bar_t);   // B4: h2 complete
  }
}

// ---------------- host ----------------

extern "C" void kernel_launch(void* const* d_in, const int* in_sizes, int n_in,
                              void* d_out, int out_size, void* d_ws, size_t ws_size,
                              hipStream_t stream){
  (void)in_sizes; (void)n_in; (void)out_size;
  if (ws_size < WS_NEED) return;

  const void* remb       = d_in[0];
  const void* re_emb     = d_in[1];
  const void* ly_mask    = d_in[2];
  const void* context    = d_in[3];
  const void* cmask      = d_in[4];
  const void* init_state = d_in[5];
  const void* Wyz_w = d_in[6];  const void* Wyz_b = d_in[7];
  const void* Wyr_w = d_in[8];  const void* Wyr_b = d_in[9];
  const void* Wyh_w = d_in[10]; const void* Wyh_b = d_in[11];
  const void* Uhz0  = d_in[12];
  const void* Uhr0  = d_in[13];
  const void* Uhh0  = d_in[14];
  const void* UaC_w = d_in[15]; const void* UaC_b = d_in[16];
  const void* WaC_w = d_in[17];
  const void* QC_w  = d_in[18];
  const void* UfC_w = d_in[19]; const void* UfC_b = d_in[20];
  const void* vaC_w = d_in[21]; const void* vaC_b = d_in[22];
  const void* Uhz2  = d_in[23]; const void* Uhz2_b = d_in[24];
  const void* Uhr2  = d_in[25]; const void* Uhr2_b = d_in[26];
  const void* Uhh2  = d_in[27]; const void* Uhh2_b = d_in[28];
  const void* Wcz   = d_in[29];
  const void* Wcr   = d_in[30];
  const void* Wch   = d_in[31];
  const int*  rp    = (const int*)d_in[32];

  char* ws = (char*)d_ws;
  float* sbp   = (float*)(ws + OFF_SB);
  float* UaCT  = (float*)(ws + OFF_TRAN);
  float* buf   = (float*)(ws + OFF_BUF);
  float* pctx  = (float*)(ws + OFF_PCTX);
  float* FKt   = (float*)(ws + OFF_FKT);
  float* rawp  = (float*)(ws + OFF_RAWP);
  float* h_ws  = (float*)(ws + OFF_H);
  float* h0_ws = (float*)(ws + OFF_H0);
  float* ap_ws = (float*)(ws + OFF_AP);
  u32*   ctrs  = (u32*)  (ws + OFF_CTR);
  int*   flag  = (int*)  (ws + OFF_FLG);
  float* out   = (float*)d_out;

  k_detect<<<1, 256, 0, stream>>>((const u16*)context, flag);
  k_tran <<<1368, 256, 0, stream>>>(UaC_w, UaCT, flag);
  k_fk   <<<18,  256, 0, stream>>>(QC_w, UfC_w, FKt, flag);
  k_pctx2<<<144, 512, 0, stream>>>(context, UaCT, UaC_b, UfC_b, pctx, flag);
  // region0 reuse: UaCT dead after k_pctx2
  k_sb   <<<768, 256, 0, stream>>>(remb, re_emb, Wyz_w, Wyz_b, Wyr_w, Wyr_b, Wyh_w, Wyh_b, sbp, flag);
  k_init <<<256, 256, 0, stream>>>(buf, ap_ws, ctrs, h_ws, init_state, flag);
  k_main <<<128, 256, 0, stream>>>(ly_mask, context, cmask,
                                   Uhz0, Uhr0, Uhh0, WaC_w, vaC_w, vaC_b,
                                   Uhz2, Uhz2_b, Uhr2, Uhr2_b, Uhh2, Uhh2_b,
                                   Wcz, Wcr, Wch, rp,
                                   pctx, sbp, FKt,
                                   buf, h_ws, h0_ws, ap_ws, rawp, ctrs, out, flag);
}